// Round 10
// baseline (171.243 us; speedup 1.0000x reference)
//
#include <hip/hip_runtime.h>
#include <hip/hip_bf16.h>

#define NN 10000
#define INDIM 128
#define HID 64
#define CAP 96    // bucket capacity; deg ~ Poisson(32), P(>96) ~ e^-60
#define CB 1250   // build blocks (E/256)
#define GB 2500   // gemm1 blocks (NN/4)

typedef __attribute__((ext_vector_type(8))) short bf16x8;
typedef __attribute__((ext_vector_type(4))) float f32x4;

__device__ __forceinline__ unsigned short f2bf(float f) {
  __hip_bfloat16 h = __float2bfloat16(f);
  return *reinterpret_cast<unsigned short*>(&h);
}

// ---- node 2: bucket-append adjacency build  ∪  gemm1 (unscaled x@W1) ----
__global__ __launch_bounds__(256) void k_build_gemm1(
    const int* __restrict__ dst, int E, int* __restrict__ cnt,
    int* __restrict__ bucket, const int* __restrict__ src,
    const float* __restrict__ x, const float* __restrict__ W1,
    float* __restrict__ xw) {
  __shared__ float w[INDIM * HID];  // 32 KB
  int b = blockIdx.x, t = threadIdx.x;
  if (b < CB) {
    int e = b * 256 + t;
    if (e < E) {
      int d = dst[e];
      int p = atomicAdd(&cnt[d], 1);
      if (p < CAP) bucket[d * CAP + p] = src[e];  // clamp: never corrupts
    }
  } else {
    for (int i = t; i < INDIM * HID; i += 256) w[i] = W1[i];
    __syncthreads();
    int r = (b - CB) * 4 + (t >> 6);
    int j = t & 63;
    float2 xv = ((const float2*)(x + (size_t)r * INDIM))[j & (INDIM / 2 - 1)];
    float acc = 0.f;
    #pragma unroll
    for (int k = 0; k < INDIM; k++) {
      float xk = __shfl((k & 1) ? xv.y : xv.x, k >> 1, 64);
      acc = fmaf(xk, w[k * HID + j], acc);
    }
    xw[(size_t)r * HID + j] = acc;   // unscaled
  }
}

// ---- node 3: agg1 (4-edge vectorized gather) + relu + gemm2, fused ----
// Lane (g,m) = (lane>>4, lane&15): one f32x4 load = 4 edges x 16 dims = 1 KB
// per instruction (4x fewer gather instrs than scalar lane=dim). Partial accs
// reduce via shfl_xor(16,32); h then lives on lanes 0-15 as f32x4 and is
// broadcast to all 64 lanes for the W2 matvec via compile-time-component shfl.
__global__ __launch_bounds__(256) void k_agg1_gemm2(
    const float* __restrict__ xw, const int* __restrict__ cnt,
    const int* __restrict__ bucket, const float* __restrict__ b1,
    const float* __restrict__ W2, float* __restrict__ hB) {
  __shared__ float w[HID * HID];  // 16 KB
  int t = threadIdx.x;
  for (int i = t; i < HID * HID; i += 256) w[i] = W2[i];
  __syncthreads();
  int wid = t >> 6, lane = t & 63;
  int g = lane >> 4, m = lane & 15;
  int d = blockIdx.x * 4 + wid;
  int c = cnt[d];
  float dis_d = rsqrtf((float)(c + 1));
  int deg = c < CAP ? c : CAP;
  const int* bk = bucket + (size_t)d * CAP;

  f32x4 acc = {0.f, 0.f, 0.f, 0.f};
  if (g == 0) {  // self-loop (scale dis_d applied with the final dis_d mul)
    f32x4 v = *(const f32x4*)(xw + (size_t)d * HID + m * 4);
    acc = v * dis_d;
  }
  for (int k = 0; k < deg; k += 4) {
    int e = k + g;
    bool ok = e < deg;
    int idx = ok ? bk[e] : d;
    float s = ok ? rsqrtf((float)(cnt[idx] + 1)) : 0.f;
    f32x4 v = *(const f32x4*)(xw + (size_t)idx * HID + m * 4);
    acc += v * s;
  }
  #pragma unroll
  for (int j = 0; j < 4; j++) {
    acc[j] += __shfl_xor(acc[j], 16, 64);
    acc[j] += __shfl_xor(acc[j], 32, 64);
  }
  // lanes 0-15: h4 = relu(acc*dis_d + b1[4m..4m+3]) (other lanes garbage, unused)
  f32x4 bb = *(const f32x4*)(b1 + m * 4);
  f32x4 h4;
  #pragma unroll
  for (int j = 0; j < 4; j++) h4[j] = fmaxf(acc[j] * dis_d + bb[j], 0.f);

  float acc2 = 0.f;
  #pragma unroll
  for (int k = 0; k < HID; k++) {
    float hk = __shfl(h4[k & 3], k >> 2, 64);  // src lane k>>2 < 16: valid h
    acc2 = fmaf(hk, w[k * HID + lane], acc2);
  }
  hB[(size_t)d * HID + lane] = acc2 * dis_d;   // carries dis_d for agg2's gather
}

// ---- node 4: agg2 (4-edge vectorized gather) + bias -> bf16 h2 ----
__global__ __launch_bounds__(256) void k_agg2(
    const float* __restrict__ hB, const int* __restrict__ cnt,
    const int* __restrict__ bucket, const float* __restrict__ b2,
    __hip_bfloat16* __restrict__ h2b) {
  int t = threadIdx.x, wid = t >> 6, lane = t & 63;
  int g = lane >> 4, m = lane & 15;
  int d = blockIdx.x * 4 + wid;
  int c = cnt[d];
  float dis_d = rsqrtf((float)(c + 1));
  int deg = c < CAP ? c : CAP;
  const int* bk = bucket + (size_t)d * CAP;

  f32x4 acc = {0.f, 0.f, 0.f, 0.f};
  if (g == 0) acc = *(const f32x4*)(hB + (size_t)d * HID + m * 4);  // self-loop
  for (int k = 0; k < deg; k += 4) {
    int e = k + g;
    bool ok = e < deg;
    int idx = ok ? bk[e] : d;
    float s = ok ? 1.f : 0.f;   // hB rows already carry dis[s]
    f32x4 v = *(const f32x4*)(hB + (size_t)idx * HID + m * 4);
    acc += v * s;
  }
  #pragma unroll
  for (int j = 0; j < 4; j++) {
    acc[j] += __shfl_xor(acc[j], 16, 64);
    acc[j] += __shfl_xor(acc[j], 32, 64);
  }
  if (g == 0) {
    f32x4 bb = *(const f32x4*)(b2 + m * 4);
    unsigned short r0 = f2bf(acc[0] * dis_d + bb[0]);
    unsigned short r1 = f2bf(acc[1] * dis_d + bb[1]);
    unsigned short r2 = f2bf(acc[2] * dis_d + bb[2]);
    unsigned short r3 = f2bf(acc[3] * dis_d + bb[3]);
    uint2 pk;
    pk.x = ((unsigned)r1 << 16) | r0;
    pk.y = ((unsigned)r3 << 16) | r2;
    *reinterpret_cast<uint2*>((unsigned short*)h2b + (size_t)d * HID + m * 4) = pk;
  }
}

// ---- node 5: out = sigmoid(h2 @ h2^T) ---- (R6 proven form)
// One wave per 64x64 tile (4x4 accs of 16x16x32 MFMA, K=64). Z symmetric:
// 16x16 subtiles stored transposed -> contiguous float4/lane; ct outer,
// rt inner. R8 proved store granularity is NOT the limiter; this form wins.
__global__ __launch_bounds__(256) void k_final(const short* __restrict__ hb,
                                               float* __restrict__ out) {
  const int T = (NN + 63) / 64;  // 157
  int wid = threadIdx.x >> 6, lane = threadIdx.x & 63;
  int tx = blockIdx.x * 2 + (wid & 1);
  int ty = blockIdx.y * 2 + (wid >> 1);
  if (tx >= T || ty >= T) return;
  int rowbase = tx * 64, colbase = ty * 64;
  int m = lane & 15, q = lane >> 4;

  bf16x8 a0[4], a1[4], b0[4], b1[4];
  #pragma unroll
  for (int rt = 0; rt < 4; rt++) {
    int r = rowbase + rt * 16 + m; r = r < NN ? r : NN - 1;
    const bf16x8* p = reinterpret_cast<const bf16x8*>(hb + (size_t)r * HID + q * 8);
    a0[rt] = p[0]; a1[rt] = p[4];
  }
  #pragma unroll
  for (int ct = 0; ct < 4; ct++) {
    int r = colbase + ct * 16 + m; r = r < NN ? r : NN - 1;
    const bf16x8* p = reinterpret_cast<const bf16x8*>(hb + (size_t)r * HID + q * 8);
    b0[ct] = p[0]; b1[ct] = p[4];
  }

  f32x4 acc[4][4];
  #pragma unroll
  for (int rt = 0; rt < 4; rt++)
    #pragma unroll
    for (int ct = 0; ct < 4; ct++) {
      f32x4 z = {0.f, 0.f, 0.f, 0.f};
      z = __builtin_amdgcn_mfma_f32_16x16x32_bf16(a0[rt], b0[ct], z, 0, 0, 0);
      z = __builtin_amdgcn_mfma_f32_16x16x32_bf16(a1[rt], b1[ct], z, 0, 0, 0);
      acc[rt][ct] = z;
    }

  #pragma unroll
  for (int ct = 0; ct < 4; ct++)
    #pragma unroll
    for (int rt = 0; rt < 4; rt++) {
      if (rowbase + rt * 16 < NN && colbase + ct * 16 < NN) {  // wave-uniform
        f32x4 z = acc[rt][ct], o;
        #pragma unroll
        for (int j = 0; j < 4; j++)
          o[j] = __builtin_amdgcn_rcpf(1.0f + __expf(-z[j]));
        size_t orow = (size_t)(colbase + ct * 16 + m);
        size_t ocol = (size_t)(rowbase + rt * 16 + q * 4);
        *reinterpret_cast<f32x4*>(out + orow * NN + ocol) = o;
      }
    }
}

extern "C" void kernel_launch(void* const* d_in, const int* in_sizes, int n_in,
                              void* d_out, int out_size, void* d_ws, size_t ws_size,
                              hipStream_t stream) {
  const float* x  = (const float*)d_in[0];
  const int*   ei = (const int*)d_in[1];
  const float* W1 = (const float*)d_in[2];
  const float* b1 = (const float*)d_in[3];
  const float* W2 = (const float*)d_in[4];
  const float* b2 = (const float*)d_in[5];
  int E = in_sizes[1] / 2;
  const int* src = ei;
  const int* dst = ei + E;

  // Scratch inside d_out (dead before k_final rewrites it); h2b in d_ws.
  char* base = (char*)d_out;
  float* xw     = (float*)(base);                        // 2.56 MB
  float* hB     = (float*)(base + 2560000);              // 2.56 MB
  int*   bucket = (int*)(base + 5120000);                // NN*CAP ints = 3.84 MB
  int*   cnt    = (int*)(base + 5120000 + (size_t)NN * CAP * 4);  // 40 KB
  __hip_bfloat16* h2b = (__hip_bfloat16*)d_ws;           // 1.28 MB

  hipMemsetAsync(cnt, 0, NN * sizeof(int), stream);                        // node 1
  k_build_gemm1<<<CB + GB, 256, 0, stream>>>(dst, E, cnt, bucket, src,
                                             x, W1, xw);                   // node 2
  k_agg1_gemm2<<<NN / 4, 256, 0, stream>>>(xw, cnt, bucket, b1, W2, hB);   // node 3
  k_agg2<<<NN / 4, 256, 0, stream>>>(hB, cnt, bucket, b2, h2b);            // node 4

  const int T = (NN + 63) / 64;           // 157
  dim3 gf((T + 1) / 2, (T + 1) / 2);      // 79 x 79, 2x2 waves of 64x64 each
  k_final<<<gf, 256, 0, stream>>>((const short*)h2b, (float*)d_out);       // node 5
}

// Round 11
// 170.780 us; speedup vs baseline: 1.0027x; 1.0027x over previous
//
#include <hip/hip_runtime.h>
#include <hip/hip_bf16.h>

#define NN 10000
#define INDIM 128
#define HID 64
#define CAP 96    // bucket capacity; deg ~ Poisson(32), P(>96) ~ e^-60
#define CB 1250   // build blocks (E/256)
#define GB 2500   // gemm1 blocks (NN/4)

typedef __attribute__((ext_vector_type(8))) short bf16x8;
typedef __attribute__((ext_vector_type(4))) float f32x4;

// ---- node 2: bucket-append adjacency build  ∪  gemm1 (unscaled x@W1) ----
__global__ __launch_bounds__(256) void k_build_gemm1(
    const int* __restrict__ dst, int E, int* __restrict__ cnt,
    int* __restrict__ bucket, const int* __restrict__ src,
    const float* __restrict__ x, const float* __restrict__ W1,
    float* __restrict__ xw) {
  __shared__ float w[INDIM * HID];  // 32 KB
  int b = blockIdx.x, t = threadIdx.x;
  if (b < CB) {
    int e = b * 256 + t;
    if (e < E) {
      int d = dst[e];
      int p = atomicAdd(&cnt[d], 1);
      if (p < CAP) bucket[d * CAP + p] = src[e];  // clamp: never corrupts
    }
  } else {
    for (int i = t; i < INDIM * HID; i += 256) w[i] = W1[i];
    __syncthreads();
    int r = (b - CB) * 4 + (t >> 6);
    int j = t & 63;
    float2 xv = ((const float2*)(x + (size_t)r * INDIM))[j & (INDIM / 2 - 1)];
    float acc = 0.f;
    #pragma unroll
    for (int k = 0; k < INDIM; k++) {
      float xk = __shfl((k & 1) ? xv.y : xv.x, k >> 1, 64);
      acc = fmaf(xk, w[k * HID + j], acc);
    }
    xw[(size_t)r * HID + j] = acc;   // unscaled
  }
}

// ---- node 3: agg1 (per-edge dis[s]) + bias + relu + gemm2 + dis[d], fused ----
// (R9 proven form; R10's 4-edge vectorized gather measured null -> reverted.)
__global__ __launch_bounds__(256) void k_agg1_gemm2(
    const float* __restrict__ xw, const int* __restrict__ cnt,
    const int* __restrict__ bucket, const float* __restrict__ b1,
    const float* __restrict__ W2, float* __restrict__ hB) {
  __shared__ float w[HID * HID];  // 16 KB
  int t = threadIdx.x;
  for (int i = t; i < HID * HID; i += 256) w[i] = W2[i];
  __syncthreads();
  int wid = t >> 6, lane = t & 63;
  int d = blockIdx.x * 4 + wid;
  int c = cnt[d];
  float dis_d = rsqrtf((float)(c + 1));
  int deg = c < CAP ? c : CAP;
  const int* bk = bucket + (size_t)d * CAP;
  float acc = xw[(size_t)d * HID + lane] * dis_d;   // self-loop
  int k = 0;
  for (; k + 8 <= deg; k += 8) {
    int i0 = bk[k],     i1 = bk[k + 1], i2 = bk[k + 2], i3 = bk[k + 3];
    int i4 = bk[k + 4], i5 = bk[k + 5], i6 = bk[k + 6], i7 = bk[k + 7];
    float s0 = rsqrtf((float)(cnt[i0] + 1)), s1 = rsqrtf((float)(cnt[i1] + 1));
    float s2 = rsqrtf((float)(cnt[i2] + 1)), s3 = rsqrtf((float)(cnt[i3] + 1));
    float s4 = rsqrtf((float)(cnt[i4] + 1)), s5 = rsqrtf((float)(cnt[i5] + 1));
    float s6 = rsqrtf((float)(cnt[i6] + 1)), s7 = rsqrtf((float)(cnt[i7] + 1));
    float v0 = xw[(size_t)i0 * HID + lane], v1 = xw[(size_t)i1 * HID + lane];
    float v2 = xw[(size_t)i2 * HID + lane], v3 = xw[(size_t)i3 * HID + lane];
    float v4 = xw[(size_t)i4 * HID + lane], v5 = xw[(size_t)i5 * HID + lane];
    float v6 = xw[(size_t)i6 * HID + lane], v7 = xw[(size_t)i7 * HID + lane];
    acc += v0 * s0 + v1 * s1 + v2 * s2 + v3 * s3
         + v4 * s4 + v5 * s5 + v6 * s6 + v7 * s7;
  }
  for (; k < deg; k++) {
    int s = bk[k];
    acc = fmaf(xw[(size_t)s * HID + lane], rsqrtf((float)(cnt[s] + 1)), acc);
  }
  float h = fmaxf(acc * dis_d + b1[lane], 0.f);
  float acc2 = 0.f;
  #pragma unroll
  for (int kk = 0; kk < HID; kk++)
    acc2 = fmaf(__shfl(h, kk, 64), w[kk * HID + lane], acc2);
  hB[(size_t)d * HID + lane] = acc2 * dis_d;   // carries dis_d for agg2's gather
}

// ---- node 4: agg2 + bias -> bf16 h2 (hB rows already carry dis[s]) ----
__global__ __launch_bounds__(256) void k_agg2(
    const float* __restrict__ hB, const int* __restrict__ cnt,
    const int* __restrict__ bucket, const float* __restrict__ b2,
    __hip_bfloat16* __restrict__ h2b) {
  int t = threadIdx.x, wid = t >> 6, lane = t & 63;
  int d = blockIdx.x * 4 + wid;
  int c = cnt[d];
  float dis_d = rsqrtf((float)(c + 1));
  int deg = c < CAP ? c : CAP;
  const int* bk = bucket + (size_t)d * CAP;
  float acc = hB[(size_t)d * HID + lane];
  int k = 0;
  for (; k + 8 <= deg; k += 8) {
    int i0 = bk[k],     i1 = bk[k + 1], i2 = bk[k + 2], i3 = bk[k + 3];
    int i4 = bk[k + 4], i5 = bk[k + 5], i6 = bk[k + 6], i7 = bk[k + 7];
    float v0 = hB[(size_t)i0 * HID + lane], v1 = hB[(size_t)i1 * HID + lane];
    float v2 = hB[(size_t)i2 * HID + lane], v3 = hB[(size_t)i3 * HID + lane];
    float v4 = hB[(size_t)i4 * HID + lane], v5 = hB[(size_t)i5 * HID + lane];
    float v6 = hB[(size_t)i6 * HID + lane], v7 = hB[(size_t)i7 * HID + lane];
    acc += ((v0 + v1) + (v2 + v3)) + ((v4 + v5) + (v6 + v7));
  }
  for (; k < deg; k++) acc += hB[(size_t)bk[k] * HID + lane];
  float v = acc * dis_d + b2[lane];
  h2b[(size_t)d * HID + lane] = __float2bfloat16(v);
}

// ---- node 5: out = sigmoid(h2 @ h2^T), occupancy-tuned ----
// Same tiling/order as the proven R6 form (wave = 64x64, ct outer / rt inner
// stores), but B-frags are loaded just-in-time per ct-column and each column's
// 4 accs are consumed immediately: register footprint drops from ~160 VGPR
// (acc[4][4] + 16 resident frags) to ~90 -> __launch_bounds__(256,4) gives
// 4 waves/SIMD instead of 3 (+33% TLP) to hide trans+store issue and B-frag
// L2 latency under the HBM write drain.
__global__ __launch_bounds__(256, 4) void k_final(const short* __restrict__ hb,
                                                  float* __restrict__ out) {
  const int T = (NN + 63) / 64;  // 157
  int wid = threadIdx.x >> 6, lane = threadIdx.x & 63;
  int tx = blockIdx.x * 2 + (wid & 1);
  int ty = blockIdx.y * 2 + (wid >> 1);
  if (tx >= T || ty >= T) return;
  int rowbase = tx * 64, colbase = ty * 64;
  int m = lane & 15, q = lane >> 4;

  bf16x8 a0[4], a1[4];
  #pragma unroll
  for (int rt = 0; rt < 4; rt++) {
    int r = rowbase + rt * 16 + m; r = r < NN ? r : NN - 1;
    const bf16x8* p = reinterpret_cast<const bf16x8*>(hb + (size_t)r * HID + q * 8);
    a0[rt] = p[0]; a1[rt] = p[4];
  }

  #pragma unroll
  for (int ct = 0; ct < 4; ct++) {
    int rr = colbase + ct * 16 + m; rr = rr < NN ? rr : NN - 1;
    const bf16x8* p = reinterpret_cast<const bf16x8*>(hb + (size_t)rr * HID + q * 8);
    bf16x8 b0 = p[0], b1 = p[4];

    f32x4 z[4];
    #pragma unroll
    for (int rt = 0; rt < 4; rt++) {
      f32x4 zz = {0.f, 0.f, 0.f, 0.f};
      zz = __builtin_amdgcn_mfma_f32_16x16x32_bf16(a0[rt], b0, zz, 0, 0, 0);
      zz = __builtin_amdgcn_mfma_f32_16x16x32_bf16(a1[rt], b1, zz, 0, 0, 0);
      z[rt] = zz;
    }

    // D[row][col]: row = rowbase+rt*16+4q+j (A side), col = colbase+ct*16+m.
    // Transposed store (Z^T == Z): out[col][row]; rt inner -> the four 64B
    // segments of each row's 256B run issue back-to-back.
    if (colbase + ct * 16 < NN) {  // wave-uniform
      #pragma unroll
      for (int rt = 0; rt < 4; rt++) {
        if (rowbase + rt * 16 < NN) {
          f32x4 o;
          #pragma unroll
          for (int j = 0; j < 4; j++)
            o[j] = __builtin_amdgcn_rcpf(1.0f + __expf(-z[rt][j]));
          size_t orow = (size_t)(colbase + ct * 16 + m);
          size_t ocol = (size_t)(rowbase + rt * 16 + q * 4);
          *reinterpret_cast<f32x4*>(out + orow * NN + ocol) = o;
        }
      }
    }
  }
}

extern "C" void kernel_launch(void* const* d_in, const int* in_sizes, int n_in,
                              void* d_out, int out_size, void* d_ws, size_t ws_size,
                              hipStream_t stream) {
  const float* x  = (const float*)d_in[0];
  const int*   ei = (const int*)d_in[1];
  const float* W1 = (const float*)d_in[2];
  const float* b1 = (const float*)d_in[3];
  const float* W2 = (const float*)d_in[4];
  const float* b2 = (const float*)d_in[5];
  int E = in_sizes[1] / 2;
  const int* src = ei;
  const int* dst = ei + E;

  // Scratch inside d_out (dead before k_final rewrites it); h2b in d_ws.
  char* base = (char*)d_out;
  float* xw     = (float*)(base);                        // 2.56 MB
  float* hB     = (float*)(base + 2560000);              // 2.56 MB
  int*   bucket = (int*)(base + 5120000);                // NN*CAP ints = 3.84 MB
  int*   cnt    = (int*)(base + 5120000 + (size_t)NN * CAP * 4);  // 40 KB
  __hip_bfloat16* h2b = (__hip_bfloat16*)d_ws;           // 1.28 MB

  hipMemsetAsync(cnt, 0, NN * sizeof(int), stream);                        // node 1
  k_build_gemm1<<<CB + GB, 256, 0, stream>>>(dst, E, cnt, bucket, src,
                                             x, W1, xw);                   // node 2
  k_agg1_gemm2<<<NN / 4, 256, 0, stream>>>(xw, cnt, bucket, b1, W2, hB);   // node 3
  k_agg2<<<NN / 4, 256, 0, stream>>>(hB, cnt, bucket, b2, h2b);            // node 4

  const int T = (NN + 63) / 64;           // 157
  dim3 gf((T + 1) / 2, (T + 1) / 2);      // 79 x 79, 2x2 waves of 64x64 each
  k_final<<<gf, 256, 0, stream>>>((const short*)h2b, (float*)d_out);       // node 5
}